// Round 1
// baseline (2396.821 us; speedup 1.0000x reference)
//
#include <hip/hip_runtime.h>
#include <hip/hip_bf16.h>

#define N_NODES 100000
#define N_EDGES 1600000
#define HDIM    128
#define NLAYER  6
#define NGRAPH  128
#define NCLASS  10
#define BN_EPS  1e-5f

#define SCAN_CHUNK 1024
#define SCAN_NB    ((N_NODES + SCAN_CHUNK - 1) / SCAN_CHUNK)   // 98
#define STAT_NB    512

// ---------------- CSR build ----------------

__global__ void k_deg(const int* __restrict__ dst, int* __restrict__ deg) {
    int e = blockIdx.x * 256 + threadIdx.x;
    if (e < N_EDGES) atomicAdd(&deg[dst[e]], 1);
}

__global__ void k_blocksum(const int* __restrict__ deg, int* __restrict__ partial) {
    int b = blockIdx.x, t = threadIdx.x;
    int s = 0;
    for (int i = 0; i < 4; ++i) {
        int g = b * SCAN_CHUNK + t * 4 + i;
        if (g < N_NODES) s += deg[g];
    }
    __shared__ int red[256];
    red[t] = s; __syncthreads();
    for (int off = 128; off > 0; off >>= 1) {
        if (t < off) red[t] += red[t + off];
        __syncthreads();
    }
    if (t == 0) partial[b] = red[0];
}

__global__ void k_scanpart(int* __restrict__ partial) {
    if (threadIdx.x == 0 && blockIdx.x == 0) {
        int acc = 0;
        for (int i = 0; i < SCAN_NB; ++i) { int v = partial[i]; partial[i] = acc; acc += v; }
    }
}

__global__ void k_scan2(const int* __restrict__ deg, const int* __restrict__ partial,
                        int* __restrict__ row_off) {
    int b = blockIdx.x, t = threadIdx.x;
    int base = b * SCAN_CHUNK;
    int v[4]; int s = 0;
    for (int i = 0; i < 4; ++i) {
        int g = base + t * 4 + i;
        v[i] = (g < N_NODES) ? deg[g] : 0;
        s += v[i];
    }
    __shared__ int ts[256];
    ts[t] = s; __syncthreads();
    for (int off = 1; off < 256; off <<= 1) {
        int x = (t >= off) ? ts[t - off] : 0;
        __syncthreads();
        ts[t] += x;
        __syncthreads();
    }
    int excl = (t > 0 ? ts[t - 1] : 0) + partial[b];
    for (int i = 0; i < 4; ++i) {
        int g = base + t * 4 + i;
        if (g < N_NODES) row_off[g] = excl;
        excl += v[i];
    }
    if (b == 0 && t == 0) row_off[N_NODES] = N_EDGES;
}

__global__ void k_fill(const int* __restrict__ src, const int* __restrict__ dst,
                       const int* __restrict__ row_off, int* __restrict__ cursor,
                       int* __restrict__ col) {
    int e = blockIdx.x * 256 + threadIdx.x;
    if (e < N_EDGES) {
        int d = dst[e];
        int pos = row_off[d] + atomicAdd(&cursor[d], 1);
        col[pos] = src[e];
    }
}

// ---------------- per-layer kernels ----------------

// one block (128 threads) per node: mean of neighbor rows
__global__ void __launch_bounds__(128) k_agg(const float* __restrict__ X,
                                             const int* __restrict__ row_off,
                                             const int* __restrict__ col,
                                             float* __restrict__ AGG) {
    int i = blockIdx.x;
    int c = threadIdx.x;
    int s = row_off[i], e = row_off[i + 1];
    __shared__ int nbrs[128];
    float acc = 0.f;
    for (int base = s; base < e; base += 128) {
        int m = e - base; if (m > 128) m = 128;
        if (c < m) nbrs[c] = col[base + c];
        __syncthreads();
        for (int j = 0; j < m; ++j)
            acc += X[(size_t)nbrs[j] * HDIM + c];
        __syncthreads();
    }
    int d = e - s;
    float w = (d > 0) ? 1.0f / (float)d : 0.f;
    AGG[(size_t)i * HDIM + c] = acc * w;
}

// H = AGG @ Wl + X @ Wr + bl   (single K=256 GEMM, f32 VALU)
#define BM 64
#define BN 64
#define BK 16
__global__ void __launch_bounds__(256) k_gemm(const float* __restrict__ AGG,
                                              const float* __restrict__ X,
                                              const float* __restrict__ Wl,
                                              const float* __restrict__ Wr,
                                              const float* __restrict__ bl,
                                              float* __restrict__ Hout) {
    __shared__ float As[BK][BM];
    __shared__ float Bs[BK][BN];
    int bm = blockIdx.x * BM;
    int bn = blockIdx.y * BN;
    int tid = threadIdx.x;
    int tm = (tid / 16) * 4;
    int tn = (tid % 16) * 4;
    float acc[4][4] = {};
    for (int k0 = 0; k0 < 256; k0 += BK) {
        const float* Asrc = (k0 < HDIM) ? AGG : X;
        const float* Bsrc = (k0 < HDIM) ? Wl : Wr;
        int ka = k0 & (HDIM - 1);
        // A tile: 64 rows x 16 k
        for (int u = tid; u < BM * BK; u += 256) {
            int m = u / BK, k = u % BK;
            int row = bm + m;
            As[k][m] = (row < N_NODES) ? Asrc[(size_t)row * HDIM + ka + k] : 0.f;
        }
        // B tile: 16 k x 64 n
        for (int u = tid; u < BK * BN; u += 256) {
            int k = u / BN, n = u % BN;
            Bs[k][n] = Bsrc[(size_t)(ka + k) * HDIM + bn + n];
        }
        __syncthreads();
#pragma unroll
        for (int k = 0; k < BK; ++k) {
            float4 a = *(const float4*)&As[k][tm];
            float4 b = *(const float4*)&Bs[k][tn];
            float av[4] = {a.x, a.y, a.z, a.w};
            float bv[4] = {b.x, b.y, b.z, b.w};
#pragma unroll
            for (int i = 0; i < 4; ++i)
#pragma unroll
                for (int j = 0; j < 4; ++j)
                    acc[i][j] += av[i] * bv[j];
        }
        __syncthreads();
    }
    for (int i = 0; i < 4; ++i) {
        int row = bm + tm + i;
        if (row >= N_NODES) break;
        for (int j = 0; j < 4; ++j)
            Hout[(size_t)row * HDIM + bn + tn + j] = acc[i][j] + bl[bn + tn + j];
    }
}

__global__ void __launch_bounds__(128) k_stats_part(const float* __restrict__ Hc,
                                                    float* __restrict__ psum,
                                                    float* __restrict__ psq) {
    int c = threadIdx.x, b = blockIdx.x;
    float s = 0.f, q = 0.f;
    for (int i = b; i < N_NODES; i += STAT_NB) {
        float v = Hc[(size_t)i * HDIM + c];
        s += v; q += v * v;
    }
    psum[b * HDIM + c] = s;
    psq[b * HDIM + c] = q;
}

__global__ void __launch_bounds__(128) k_stats_final(const float* __restrict__ psum,
                                                     const float* __restrict__ psq,
                                                     const float* __restrict__ gamma,
                                                     const float* __restrict__ beta,
                                                     float* __restrict__ scsh) {
    int c = threadIdx.x;
    float s = 0.f, q = 0.f;
    for (int b = 0; b < STAT_NB; ++b) { s += psum[b * HDIM + c]; q += psq[b * HDIM + c]; }
    float mu = s / (float)N_NODES;
    float var = q / (float)N_NODES - mu * mu;
    float rs = rsqrtf(var + BN_EPS);
    float sc = gamma[c] * rs;
    scsh[c] = sc;
    scsh[HDIM + c] = beta[c] - mu * sc;
}

__global__ void __launch_bounds__(256) k_bn_relu(float* __restrict__ Hio,
                                                 const float* __restrict__ scsh) {
    int idx = blockIdx.x * 256 + threadIdx.x;          // float4 index
    if (idx >= N_NODES * HDIM / 4) return;
    int c4 = (idx & 31) * 4;
    float4 v = ((const float4*)Hio)[idx];
    float4 o;
    o.x = fmaxf(0.f, v.x * scsh[c4 + 0] + scsh[HDIM + c4 + 0]);
    o.y = fmaxf(0.f, v.y * scsh[c4 + 1] + scsh[HDIM + c4 + 1]);
    o.z = fmaxf(0.f, v.z * scsh[c4 + 2] + scsh[HDIM + c4 + 2]);
    o.w = fmaxf(0.f, v.w * scsh[c4 + 3] + scsh[HDIM + c4 + 3]);
    ((float4*)Hio)[idx] = o;
}

// ---------------- pooling + classifier ----------------

__device__ __forceinline__ int lbound(const int* __restrict__ a, int key) {
    int lo = 0, hi = N_NODES;
    while (lo < hi) { int mid = (lo + hi) >> 1; if (a[mid] < key) lo = mid + 1; else hi = mid; }
    return lo;
}

__global__ void __launch_bounds__(128) k_pool(const float* __restrict__ X,
                                              const int* __restrict__ batch,
                                              float* __restrict__ pooled) {
    int g = blockIdx.x, c = threadIdx.x;
    int s = lbound(batch, g);
    int e = lbound(batch, g + 1);
    float acc = 0.f;
    for (int i = s; i < e; ++i) acc += X[(size_t)i * HDIM + c];
    int cnt = e - s; if (cnt < 1) cnt = 1;
    pooled[g * HDIM + c] = acc / (float)cnt;
}

__global__ void __launch_bounds__(128) k_lin(const float* __restrict__ pooled,
                                             const float* __restrict__ W,
                                             const float* __restrict__ bvec,
                                             float* __restrict__ out) {
    __shared__ float p[HDIM];
    int g = blockIdx.x, t = threadIdx.x;
    p[t] = pooled[g * HDIM + t];
    __syncthreads();
    if (t < NCLASS) {
        float acc = bvec[t];
        for (int k = 0; k < HDIM; ++k) acc += p[k] * W[k * NCLASS + t];
        out[g * NCLASS + t] = acc;
    }
}

// ---------------- launch ----------------

extern "C" void kernel_launch(void* const* d_in, const int* in_sizes, int n_in,
                              void* d_out, int out_size, void* d_ws, size_t ws_size,
                              hipStream_t stream) {
    const float* x     = (const float*)d_in[0];
    const int*   eidx  = (const int*)d_in[1];
    const int*   batch = (const int*)d_in[2];
    const float* Wl    = (const float*)d_in[3];
    const float* bl    = (const float*)d_in[4];
    const float* Wr    = (const float*)d_in[5];
    const float* gamma = (const float*)d_in[6];
    const float* beta  = (const float*)d_in[7];
    const float* linW  = (const float*)d_in[8];
    const float* linb  = (const float*)d_in[9];
    float* out = (float*)d_out;

    const int* src = eidx;
    const int* dst = eidx + N_EDGES;

    // workspace layout
    float* AGG = (float*)d_ws;
    float* B0  = AGG + (size_t)N_NODES * HDIM;
    float* B1  = B0  + (size_t)N_NODES * HDIM;
    int* row_off = (int*)(B1 + (size_t)N_NODES * HDIM);
    int* deg     = row_off + (N_NODES + 2);
    int* cursor  = deg + N_NODES;
    int* col     = cursor + N_NODES;
    int* part    = col + N_EDGES;
    float* psum  = (float*)(part + 128);
    float* psq   = psum + STAT_NB * HDIM;
    float* scsh  = psq  + STAT_NB * HDIM;
    float* pooled = scsh + 2 * HDIM;

    // ---- CSR build (per call; deterministic up to neighbor order) ----
    hipMemsetAsync(deg, 0, N_NODES * sizeof(int), stream);
    hipMemsetAsync(cursor, 0, N_NODES * sizeof(int), stream);
    k_deg<<<(N_EDGES + 255) / 256, 256, 0, stream>>>(dst, deg);
    k_blocksum<<<SCAN_NB, 256, 0, stream>>>(deg, part);
    k_scanpart<<<1, 64, 0, stream>>>(part);
    k_scan2<<<SCAN_NB, 256, 0, stream>>>(deg, part, row_off);
    k_fill<<<(N_EDGES + 255) / 256, 256, 0, stream>>>(src, dst, row_off, cursor, col);

    // ---- layers ----
    const float* Xin = x;
    for (int l = 0; l < NLAYER; ++l) {
        float* Hc = (l & 1) ? B1 : B0;
        k_agg<<<N_NODES, 128, 0, stream>>>(Xin, row_off, col, AGG);
        k_gemm<<<dim3((N_NODES + BM - 1) / BM, HDIM / BN), 256, 0, stream>>>(
            AGG, Xin, Wl + (size_t)l * HDIM * HDIM, Wr + (size_t)l * HDIM * HDIM,
            bl + (size_t)l * HDIM, Hc);
        k_stats_part<<<STAT_NB, 128, 0, stream>>>(Hc, psum, psq);
        k_stats_final<<<1, 128, 0, stream>>>(psum, psq, gamma + (size_t)l * HDIM,
                                             beta + (size_t)l * HDIM, scsh);
        k_bn_relu<<<(N_NODES * HDIM / 4 + 255) / 256, 256, 0, stream>>>(Hc, scsh);
        Xin = Hc;
    }

    // ---- pool + classifier ----
    k_pool<<<NGRAPH, 128, 0, stream>>>(Xin, batch, pooled);
    k_lin<<<NGRAPH, 128, 0, stream>>>(pooled, linW, linb, out);
}

// Round 2
// 1380.083 us; speedup vs baseline: 1.7367x; 1.7367x over previous
//
#include <hip/hip_runtime.h>
#include <hip/hip_bf16.h>

#define N_NODES 100000
#define N_EDGES 1600000
#define HDIM    128
#define NLAYER  6
#define NGRAPH  128
#define NCLASS  10
#define BN_EPS  1e-5f

#define SCAN_CHUNK 1024
#define SCAN_NB    ((N_NODES + SCAN_CHUNK - 1) / SCAN_CHUNK)   // 98
#define STAT_NB    512
#define POOL_SPLIT 16

typedef __attribute__((ext_vector_type(8))) short short8v;
typedef __attribute__((ext_vector_type(4))) float f32x4;

__device__ __forceinline__ float b2f(unsigned short h) {
    return __uint_as_float(((unsigned int)h) << 16);
}
__device__ __forceinline__ unsigned short f2b(float f) {
    unsigned int u = __float_as_uint(f);
    u += 0x7FFF + ((u >> 16) & 1);          // RNE
    return (unsigned short)(u >> 16);
}
__device__ __forceinline__ void gl_lds16(const void* g, void* l) {
    __builtin_amdgcn_global_load_lds((const __attribute__((address_space(1))) unsigned int*)g,
                                     (__attribute__((address_space(3))) unsigned int*)l,
                                     16, 0, 0);
}

// ---------------- CSR build ----------------

__global__ void k_deg(const int* __restrict__ dst, int* __restrict__ deg) {
    int e = blockIdx.x * 256 + threadIdx.x;
    if (e < N_EDGES) atomicAdd(&deg[dst[e]], 1);
}

__global__ void k_blocksum(const int* __restrict__ deg, int* __restrict__ partial) {
    int b = blockIdx.x, t = threadIdx.x;
    int s = 0;
    for (int i = 0; i < 4; ++i) {
        int g = b * SCAN_CHUNK + t * 4 + i;
        if (g < N_NODES) s += deg[g];
    }
    __shared__ int red[256];
    red[t] = s; __syncthreads();
    for (int off = 128; off > 0; off >>= 1) {
        if (t < off) red[t] += red[t + off];
        __syncthreads();
    }
    if (t == 0) partial[b] = red[0];
}

__global__ void k_scanpart(int* __restrict__ partial) {
    if (threadIdx.x == 0 && blockIdx.x == 0) {
        int acc = 0;
        for (int i = 0; i < SCAN_NB; ++i) { int v = partial[i]; partial[i] = acc; acc += v; }
    }
}

__global__ void k_scan2(const int* __restrict__ deg, const int* __restrict__ partial,
                        int* __restrict__ row_off) {
    int b = blockIdx.x, t = threadIdx.x;
    int base = b * SCAN_CHUNK;
    int v[4]; int s = 0;
    for (int i = 0; i < 4; ++i) {
        int g = base + t * 4 + i;
        v[i] = (g < N_NODES) ? deg[g] : 0;
        s += v[i];
    }
    __shared__ int ts[256];
    ts[t] = s; __syncthreads();
    for (int off = 1; off < 256; off <<= 1) {
        int x = (t >= off) ? ts[t - off] : 0;
        __syncthreads();
        ts[t] += x;
        __syncthreads();
    }
    int excl = (t > 0 ? ts[t - 1] : 0) + partial[b];
    for (int i = 0; i < 4; ++i) {
        int g = base + t * 4 + i;
        if (g < N_NODES) row_off[g] = excl;
        excl += v[i];
    }
    if (b == 0 && t == 0) row_off[N_NODES] = N_EDGES;
}

__global__ void k_fill(const int* __restrict__ src, const int* __restrict__ dst,
                       const int* __restrict__ row_off, int* __restrict__ cursor,
                       int* __restrict__ col) {
    int e = blockIdx.x * 256 + threadIdx.x;
    if (e < N_EDGES) {
        int d = dst[e];
        int pos = row_off[d] + atomicAdd(&cursor[d], 1);
        col[pos] = src[e];
    }
}

// ---------------- one-time converts ----------------

__global__ void __launch_bounds__(256) k_cvt_x(const float* __restrict__ x,
                                               unsigned short* __restrict__ Xb) {
    int idx = blockIdx.x * 256 + threadIdx.x;          // < N*H/4
    float4 v = ((const float4*)x)[idx];
    ushort4 o = { f2b(v.x), f2b(v.y), f2b(v.z), f2b(v.w) };
    ((ushort4*)Xb)[idx] = o;
}

// Wtb[l][n][kk] (kk<128 -> Wl[l][kk][n], else Wr[l][kk-128][n]), bf16
__global__ void __launch_bounds__(256) k_cvt_w(const float* __restrict__ Wl,
                                               const float* __restrict__ Wr,
                                               unsigned short* __restrict__ Wtb) {
    int idx = blockIdx.x * 256 + threadIdx.x;          // < 6*128*256
    int kk = idx & 255;
    int n  = (idx >> 8) & 127;
    int l  = idx >> 15;
    float v = (kk < HDIM) ? Wl[l * HDIM * HDIM + kk * HDIM + n]
                          : Wr[l * HDIM * HDIM + (kk - HDIM) * HDIM + n];
    Wtb[idx] = f2b(v);
}

// ---------------- per-layer kernels ----------------

// 8 nodes per block, 32 threads per node, ushort4 (4 channels) per thread
__global__ void __launch_bounds__(256) k_agg(const unsigned short* __restrict__ Xb,
                                             const int* __restrict__ row_off,
                                             const int* __restrict__ col,
                                             unsigned short* __restrict__ AGGb) {
    int node = blockIdx.x * 8 + (threadIdx.x >> 5);
    int t = threadIdx.x & 31;
    if (node >= N_NODES) return;
    int s = row_off[node], e = row_off[node + 1];
    float a0 = 0.f, a1 = 0.f, a2 = 0.f, a3 = 0.f;
    for (int p = s; p < e; ++p) {
        int nbr = col[p];
        ushort4 v = *(const ushort4*)(Xb + (size_t)nbr * HDIM + t * 4);
        a0 += b2f(v.x); a1 += b2f(v.y); a2 += b2f(v.z); a3 += b2f(v.w);
    }
    float w = (e > s) ? 1.0f / (float)(e - s) : 0.f;
    ushort4 o = { f2b(a0 * w), f2b(a1 * w), f2b(a2 * w), f2b(a3 * w) };
    *(ushort4*)(AGGb + (size_t)node * HDIM + t * 4) = o;
}

// H[M,128] = [AGGb|Xb] (K=256, bf16) @ Wtb^T + bl ;  MFMA 16x16x32 bf16
#define GBM 64
__global__ void __launch_bounds__(256) k_gemm(const unsigned short* __restrict__ AGGb,
                                              const unsigned short* __restrict__ Xb,
                                              const unsigned short* __restrict__ Wtb,
                                              const float* __restrict__ bl,
                                              float* __restrict__ H) {
    // LDS: A tile [64 rows][32 k] bf16 (4KB) + Wt tile [128 n][32 k] bf16 (8KB),
    // both XOR-swizzled: 16B slot ^= (row&3)  (pre-swizzled global source, linear LDS dest)
    __shared__ __align__(16) char smem[12288];
    const int tid  = threadIdx.x;
    const int bm   = blockIdx.x * GBM;
    const int wv   = tid >> 6;
    const int lane = tid & 63;
    const int li   = lane & 15, hi = lane >> 4;
    const int wm   = wv & 1,  wn = wv >> 1;

    f32x4 acc[2][4] = {};

    const int rA = tid >> 2, sA = tid & 3;
    int rowA = bm + rA; if (rowA >= N_NODES) rowA = N_NODES - 1;
    const int swzA = ((sA ^ (rA & 3)) << 4);
    char* ldsA = smem + wv * 1024;

    for (int step = 0; step < 8; ++step) {
        const unsigned short* Asrc = (step < 4) ? AGGb : Xb;
        const int kk0 = (step & 3) * 32;
        gl_lds16((const char*)(Asrc + (size_t)rowA * HDIM + kk0) + swzA, ldsA);
        const int k0f = step * 32;
#pragma unroll
        for (int q = 0; q < 2; ++q) {
            int L2 = q * 256 + tid;
            int rW = L2 >> 2, sW = L2 & 3;
            gl_lds16((const char*)(Wtb + (size_t)rW * 256 + k0f) + ((sW ^ (rW & 3)) << 4),
                     smem + 4096 + q * 4096 + wv * 1024);
        }
        __syncthreads();

        short8v afr[2], bfr[4];
#pragma unroll
        for (int m = 0; m < 2; ++m) {
            int r = wm * 32 + m * 16 + li;
            afr[m] = *(const short8v*)(smem + r * 64 + ((hi ^ (r & 3)) << 4));
        }
#pragma unroll
        for (int nf = 0; nf < 4; ++nf) {
            int r = wn * 64 + nf * 16 + li;
            bfr[nf] = *(const short8v*)(smem + 4096 + r * 64 + ((hi ^ (r & 3)) << 4));
        }
#pragma unroll
        for (int m = 0; m < 2; ++m)
#pragma unroll
            for (int nf = 0; nf < 4; ++nf)
                acc[m][nf] = __builtin_amdgcn_mfma_f32_16x16x32_bf16(afr[m], bfr[nf],
                                                                     acc[m][nf], 0, 0, 0);
        __syncthreads();
    }

    // epilogue: C layout col = lane&15, row = (lane>>4)*4 + reg  [m89-verified]
#pragma unroll
    for (int m = 0; m < 2; ++m) {
        int row0 = bm + wm * 32 + m * 16 + hi * 4;
#pragma unroll
        for (int nf = 0; nf < 4; ++nf) {
            int c = wn * 64 + nf * 16 + li;
            float bb = bl[c];
#pragma unroll
            for (int j = 0; j < 4; ++j) {
                int row = row0 + j;
                if (row < N_NODES) H[(size_t)row * HDIM + c] = acc[m][nf][j] + bb;
            }
        }
    }
}

__global__ void __launch_bounds__(128) k_stats_part(const float* __restrict__ Hc,
                                                    float* __restrict__ psum,
                                                    float* __restrict__ psq) {
    int c = threadIdx.x, b = blockIdx.x;
    float s = 0.f, q = 0.f;
    for (int i = b; i < N_NODES; i += STAT_NB) {
        float v = Hc[(size_t)i * HDIM + c];
        s += v; q += v * v;
    }
    psum[b * HDIM + c] = s;
    psq[b * HDIM + c] = q;
}

__global__ void __launch_bounds__(128) k_stats_final(const float* __restrict__ psum,
                                                     const float* __restrict__ psq,
                                                     const float* __restrict__ gamma,
                                                     const float* __restrict__ beta,
                                                     float* __restrict__ scsh) {
    int c = threadIdx.x;
    float s = 0.f, q = 0.f;
    for (int b = 0; b < STAT_NB; ++b) { s += psum[b * HDIM + c]; q += psq[b * HDIM + c]; }
    float mu = s / (float)N_NODES;
    float var = q / (float)N_NODES - mu * mu;
    float rs = rsqrtf(var + BN_EPS);
    float sc = gamma[c] * rs;
    scsh[c] = sc;
    scsh[HDIM + c] = beta[c] - mu * sc;
}

// read H (f32), write next activation Xb (bf16)
__global__ void __launch_bounds__(256) k_bn_relu(const float* __restrict__ Hin,
                                                 const float* __restrict__ scsh,
                                                 unsigned short* __restrict__ Xb) {
    int idx = blockIdx.x * 256 + threadIdx.x;          // float4 index
    int c4 = (idx & 31) * 4;
    float4 v = ((const float4*)Hin)[idx];
    ushort4 o;
    o.x = f2b(fmaxf(0.f, v.x * scsh[c4 + 0] + scsh[HDIM + c4 + 0]));
    o.y = f2b(fmaxf(0.f, v.y * scsh[c4 + 1] + scsh[HDIM + c4 + 1]));
    o.z = f2b(fmaxf(0.f, v.z * scsh[c4 + 2] + scsh[HDIM + c4 + 2]));
    o.w = f2b(fmaxf(0.f, v.w * scsh[c4 + 3] + scsh[HDIM + c4 + 3]));
    ((ushort4*)Xb)[idx] = o;
}

// ---------------- pooling + classifier ----------------

__global__ void k_gbound(const int* __restrict__ batch, int* __restrict__ gb) {
    int t = blockIdx.x * 64 + threadIdx.x;
    if (t > NGRAPH) return;
    int lo = 0, hi = N_NODES;
    while (lo < hi) { int mid = (lo + hi) >> 1; if (batch[mid] < t) lo = mid + 1; else hi = mid; }
    gb[t] = lo;
}

__global__ void __launch_bounds__(128) k_pool_part(const unsigned short* __restrict__ Xb,
                                                   const int* __restrict__ gb,
                                                   float* __restrict__ ppart) {
    int g = blockIdx.x, sp = blockIdx.y;
    int c = threadIdx.x;
    int s = gb[g], e = gb[g + 1];
    float acc = 0.f;
    for (int i = s + sp; i < e; i += POOL_SPLIT)
        acc += b2f(Xb[(size_t)i * HDIM + c]);
    ppart[(g * POOL_SPLIT + sp) * HDIM + c] = acc;
}

__global__ void __launch_bounds__(128) k_pool_final(const int* __restrict__ gb,
                                                    const float* __restrict__ ppart,
                                                    float* __restrict__ pooled) {
    int g = blockIdx.x, c = threadIdx.x;
    float s = 0.f;
    for (int sp = 0; sp < POOL_SPLIT; ++sp) s += ppart[(g * POOL_SPLIT + sp) * HDIM + c];
    int cnt = gb[g + 1] - gb[g]; if (cnt < 1) cnt = 1;
    pooled[g * HDIM + c] = s / (float)cnt;
}

__global__ void __launch_bounds__(128) k_lin(const float* __restrict__ pooled,
                                             const float* __restrict__ W,
                                             const float* __restrict__ bvec,
                                             float* __restrict__ out) {
    __shared__ float p[HDIM];
    int g = blockIdx.x, t = threadIdx.x;
    p[t] = pooled[g * HDIM + t];
    __syncthreads();
    if (t < NCLASS) {
        float acc = bvec[t];
        for (int k = 0; k < HDIM; ++k) acc += p[k] * W[k * NCLASS + t];
        out[g * NCLASS + t] = acc;
    }
}

// ---------------- launch ----------------

extern "C" void kernel_launch(void* const* d_in, const int* in_sizes, int n_in,
                              void* d_out, int out_size, void* d_ws, size_t ws_size,
                              hipStream_t stream) {
    const float* x     = (const float*)d_in[0];
    const int*   eidx  = (const int*)d_in[1];
    const int*   batch = (const int*)d_in[2];
    const float* Wl    = (const float*)d_in[3];
    const float* bl    = (const float*)d_in[4];
    const float* Wr    = (const float*)d_in[5];
    const float* gamma = (const float*)d_in[6];
    const float* beta  = (const float*)d_in[7];
    const float* linW  = (const float*)d_in[8];
    const float* linb  = (const float*)d_in[9];
    float* out = (float*)d_out;

    const int* src = eidx;
    const int* dst = eidx + N_EDGES;

    // workspace layout (256B-aligned chunks)
    char* p = (char*)d_ws;
    auto alloc = [&](size_t bytes) { char* r = p; p += (bytes + 255) & ~(size_t)255; return r; };
    unsigned short* Xb   = (unsigned short*)alloc((size_t)N_NODES * HDIM * 2);
    unsigned short* AGGb = (unsigned short*)alloc((size_t)N_NODES * HDIM * 2);
    float*          H    = (float*)alloc((size_t)N_NODES * HDIM * 4);
    unsigned short* Wtb  = (unsigned short*)alloc((size_t)NLAYER * 2 * HDIM * HDIM * 2);
    int* row_off = (int*)alloc((N_NODES + 2) * 4);
    int* deg     = (int*)alloc(N_NODES * 4);
    int* cursor  = (int*)alloc(N_NODES * 4);
    int* col     = (int*)alloc((size_t)N_EDGES * 4);
    int* part    = (int*)alloc(SCAN_NB * 4);
    int* gb      = (int*)alloc((NGRAPH + 2) * 4);
    float* psum  = (float*)alloc(STAT_NB * HDIM * 4);
    float* psq   = (float*)alloc(STAT_NB * HDIM * 4);
    float* scsh  = (float*)alloc(2 * HDIM * 4);
    float* ppart = (float*)alloc((size_t)NGRAPH * POOL_SPLIT * HDIM * 4);
    float* pooled= (float*)alloc(NGRAPH * HDIM * 4);

    // ---- CSR build ----
    hipMemsetAsync(deg, 0, N_NODES * sizeof(int), stream);
    hipMemsetAsync(cursor, 0, N_NODES * sizeof(int), stream);
    k_deg<<<(N_EDGES + 255) / 256, 256, 0, stream>>>(dst, deg);
    k_blocksum<<<SCAN_NB, 256, 0, stream>>>(deg, part);
    k_scanpart<<<1, 64, 0, stream>>>(part);
    k_scan2<<<SCAN_NB, 256, 0, stream>>>(deg, part, row_off);
    k_fill<<<(N_EDGES + 255) / 256, 256, 0, stream>>>(src, dst, row_off, cursor, col);

    // ---- one-time converts ----
    k_cvt_x<<<N_NODES * HDIM / 4 / 256, 256, 0, stream>>>(x, Xb);
    k_cvt_w<<<NLAYER * 2 * HDIM * HDIM / 256, 256, 0, stream>>>(Wl, Wr, Wtb);
    k_gbound<<<3, 64, 0, stream>>>(batch, gb);

    // ---- layers ----
    for (int l = 0; l < NLAYER; ++l) {
        k_agg<<<N_NODES / 8, 256, 0, stream>>>(Xb, row_off, col, AGGb);
        k_gemm<<<(N_NODES + GBM - 1) / GBM, 256, 0, stream>>>(
            AGGb, Xb, Wtb + (size_t)l * 2 * HDIM * HDIM, bl + (size_t)l * HDIM, H);
        k_stats_part<<<STAT_NB, 128, 0, stream>>>(H, psum, psq);
        k_stats_final<<<1, 128, 0, stream>>>(psum, psq, gamma + (size_t)l * HDIM,
                                             beta + (size_t)l * HDIM, scsh);
        k_bn_relu<<<N_NODES * HDIM / 4 / 256, 256, 0, stream>>>(H, scsh, Xb);
    }

    // ---- pool + classifier ----
    k_pool_part<<<dim3(NGRAPH, POOL_SPLIT), 128, 0, stream>>>(Xb, gb, ppart);
    k_pool_final<<<NGRAPH, 128, 0, stream>>>(gb, ppart, pooled);
    k_lin<<<NGRAPH, 128, 0, stream>>>(pooled, linW, linb, out);
}

// Round 3
// 890.649 us; speedup vs baseline: 2.6911x; 1.5495x over previous
//
#include <hip/hip_runtime.h>
#include <hip/hip_bf16.h>

#define N_NODES 100000
#define N_EDGES 1600000
#define HDIM    128
#define NLAYER  6
#define NGRAPH  128
#define NCLASS  10
#define BN_EPS  1e-5f

#define SCAN_CHUNK 1024
#define SCAN_NB    ((N_NODES + SCAN_CHUNK - 1) / SCAN_CHUNK)   // 98
#define POOL_SPLIT 16

#define GBM 128
#define NBLK_G ((N_NODES + GBM - 1) / GBM)                     // 782

typedef __attribute__((ext_vector_type(8))) short short8v;
typedef __attribute__((ext_vector_type(4))) float f32x4;

__device__ __forceinline__ float b2f(unsigned short h) {
    return __uint_as_float(((unsigned int)h) << 16);
}
__device__ __forceinline__ unsigned short f2b(float f) {
    unsigned int u = __float_as_uint(f);
    u += 0x7FFF + ((u >> 16) & 1);          // RNE
    return (unsigned short)(u >> 16);
}
__device__ __forceinline__ void gl_lds16(const void* g, void* l) {
    __builtin_amdgcn_global_load_lds((const __attribute__((address_space(1))) unsigned int*)g,
                                     (__attribute__((address_space(3))) unsigned int*)l,
                                     16, 0, 0);
}

// ---------------- CSR build ----------------

__global__ void k_deg(const int* __restrict__ dst, int* __restrict__ deg) {
    int e = blockIdx.x * 256 + threadIdx.x;
    if (e < N_EDGES) atomicAdd(&deg[dst[e]], 1);
}

__global__ void k_blocksum(const int* __restrict__ deg, int* __restrict__ partial) {
    int b = blockIdx.x, t = threadIdx.x;
    int s = 0;
    for (int i = 0; i < 4; ++i) {
        int g = b * SCAN_CHUNK + t * 4 + i;
        if (g < N_NODES) s += deg[g];
    }
    __shared__ int red[256];
    red[t] = s; __syncthreads();
    for (int off = 128; off > 0; off >>= 1) {
        if (t < off) red[t] += red[t + off];
        __syncthreads();
    }
    if (t == 0) partial[b] = red[0];
}

__global__ void k_scanpart(int* __restrict__ partial) {
    if (threadIdx.x == 0 && blockIdx.x == 0) {
        int acc = 0;
        for (int i = 0; i < SCAN_NB; ++i) { int v = partial[i]; partial[i] = acc; acc += v; }
    }
}

__global__ void k_scan2(const int* __restrict__ deg, const int* __restrict__ partial,
                        int* __restrict__ row_off) {
    int b = blockIdx.x, t = threadIdx.x;
    int base = b * SCAN_CHUNK;
    int v[4]; int s = 0;
    for (int i = 0; i < 4; ++i) {
        int g = base + t * 4 + i;
        v[i] = (g < N_NODES) ? deg[g] : 0;
        s += v[i];
    }
    __shared__ int ts[256];
    ts[t] = s; __syncthreads();
    for (int off = 1; off < 256; off <<= 1) {
        int x = (t >= off) ? ts[t - off] : 0;
        __syncthreads();
        ts[t] += x;
        __syncthreads();
    }
    int excl = (t > 0 ? ts[t - 1] : 0) + partial[b];
    for (int i = 0; i < 4; ++i) {
        int g = base + t * 4 + i;
        if (g < N_NODES) row_off[g] = excl;
        excl += v[i];
    }
    if (b == 0 && t == 0) row_off[N_NODES] = N_EDGES;
}

__global__ void k_fill(const int* __restrict__ src, const int* __restrict__ dst,
                       const int* __restrict__ row_off, int* __restrict__ cursor,
                       int* __restrict__ col) {
    int e = blockIdx.x * 256 + threadIdx.x;
    if (e < N_EDGES) {
        int d = dst[e];
        int pos = row_off[d] + atomicAdd(&cursor[d], 1);
        col[pos] = src[e];
    }
}

// ---------------- one-time converts ----------------

__global__ void __launch_bounds__(256) k_cvt_x(const float* __restrict__ x,
                                               unsigned short* __restrict__ Xb) {
    int idx = blockIdx.x * 256 + threadIdx.x;          // < N*H/4
    float4 v = ((const float4*)x)[idx];
    ushort4 o = { f2b(v.x), f2b(v.y), f2b(v.z), f2b(v.w) };
    ((ushort4*)Xb)[idx] = o;
}

// Wtb[l][n][kk] (kk<128 -> Wl[l][kk][n], else Wr[l][kk-128][n]), bf16
__global__ void __launch_bounds__(256) k_cvt_w(const float* __restrict__ Wl,
                                               const float* __restrict__ Wr,
                                               unsigned short* __restrict__ Wtb) {
    int idx = blockIdx.x * 256 + threadIdx.x;          // < 6*128*256
    int kk = idx & 255;
    int n  = (idx >> 8) & 127;
    int l  = idx >> 15;
    float v = (kk < HDIM) ? Wl[l * HDIM * HDIM + kk * HDIM + n]
                          : Wr[l * HDIM * HDIM + (kk - HDIM) * HDIM + n];
    Wtb[idx] = f2b(v);
}

// ---------------- per-layer kernels ----------------

// 16 nodes per block, 16 threads per node, ushort8 (8 channels, 16B) per thread
__global__ void __launch_bounds__(256) k_agg(const unsigned short* __restrict__ Xb,
                                             const int* __restrict__ row_off,
                                             const int* __restrict__ col,
                                             unsigned short* __restrict__ AGGb) {
    int node = blockIdx.x * 16 + (threadIdx.x >> 4);
    int t = threadIdx.x & 15;
    int s = row_off[node], e = row_off[node + 1];
    float a[8] = {};
    int p = s;
    for (; p + 2 <= e; p += 2) {
        int n0 = col[p], n1 = col[p + 1];
        short8v v0 = *(const short8v*)(Xb + (size_t)n0 * HDIM + t * 8);
        short8v v1 = *(const short8v*)(Xb + (size_t)n1 * HDIM + t * 8);
#pragma unroll
        for (int j = 0; j < 8; ++j) a[j] += b2f((unsigned short)v0[j]);
#pragma unroll
        for (int j = 0; j < 8; ++j) a[j] += b2f((unsigned short)v1[j]);
    }
    if (p < e) {
        int n0 = col[p];
        short8v v0 = *(const short8v*)(Xb + (size_t)n0 * HDIM + t * 8);
#pragma unroll
        for (int j = 0; j < 8; ++j) a[j] += b2f((unsigned short)v0[j]);
    }
    float w = (e > s) ? 1.0f / (float)(e - s) : 0.f;
    short8v o;
#pragma unroll
    for (int j = 0; j < 8; ++j) o[j] = (short)f2b(a[j] * w);
    *(short8v*)(AGGb + (size_t)node * HDIM + t * 8) = o;
}

// H[M,128](bf16) = [AGGb|Xb] (K=256 bf16) @ Wtb^T + bl, fused BN-stat partials.
// 128 rows/block, K-step 32, LDS double-buffered, 1 barrier/step.
__global__ void __launch_bounds__(256) k_gemm_f(const unsigned short* __restrict__ AGGb,
                                                const unsigned short* __restrict__ Xb,
                                                const unsigned short* __restrict__ Wtb,
                                                const float* __restrict__ bl,
                                                unsigned short* __restrict__ Hb,
                                                float* __restrict__ pstat) {
    // per buffer: A [128 rows][32 k] bf16 = 8KB, W [128 n][32 k] bf16 = 8KB
    __shared__ __align__(16) char smem[32768];
    const int tid  = threadIdx.x;
    const int bm   = blockIdx.x * GBM;
    const int wv   = tid >> 6;
    const int lane = tid & 63;
    const int li   = lane & 15, hi = lane >> 4;

    f32x4 acc[2][8] = {};

    // staging slot for this thread (slot s = q*256 + tid, row = s>>2, 16B slot sk = s&3)
    const int rA0 = tid >> 2, sk0 = tid & 3;

    // stage one step into buffer b
    auto stage = [&](int b, int step) {
        const unsigned short* Asrc = (step < 4) ? AGGb : Xb;
        const int kk0 = (step & 3) * 32;
        char* base = smem + b * 16384;
#pragma unroll
        for (int q = 0; q < 2; ++q) {
            int s = q * 256 + tid;
            int r = s >> 2, sk = s & 3;
            int row = bm + r; if (row >= N_NODES) row = N_NODES - 1;
            gl_lds16((const char*)(Asrc + (size_t)row * HDIM + kk0) + (((sk ^ (r & 3)) & 3) << 4),
                     base + (q * 4 + wv) * 1024);
        }
        const int k0 = step * 32;
#pragma unroll
        for (int q = 0; q < 2; ++q) {
            int s = q * 256 + tid;
            int n = s >> 2, sk = s & 3;
            gl_lds16((const char*)(Wtb + (size_t)n * 256 + k0) + (((sk ^ (n & 3)) & 3) << 4),
                     base + 8192 + (q * 4 + wv) * 1024);
        }
        (void)rA0; (void)sk0;
    };

    stage(0, 0);
    __syncthreads();

    int buf = 0;
    for (int step = 0; step < 8; ++step) {
        if (step < 7) stage(buf ^ 1, step + 1);
        char* bA = smem + buf * 16384;
        char* bW = bA + 8192;
        short8v afr[2], bfr[8];
#pragma unroll
        for (int m = 0; m < 2; ++m) {
            int r = wv * 32 + m * 16 + li;
            afr[m] = *(const short8v*)(bA + r * 64 + ((hi ^ (r & 3)) << 4));
        }
#pragma unroll
        for (int nf = 0; nf < 8; ++nf) {
            int n = nf * 16 + li;
            bfr[nf] = *(const short8v*)(bW + n * 64 + ((hi ^ (n & 3)) << 4));
        }
#pragma unroll
        for (int m = 0; m < 2; ++m)
#pragma unroll
            for (int nf = 0; nf < 8; ++nf)
                acc[m][nf] = __builtin_amdgcn_mfma_f32_16x16x32_bf16(afr[m], bfr[nf],
                                                                     acc[m][nf], 0, 0, 0);
        __syncthreads();
        buf ^= 1;
    }

    // epilogue: C layout col = lane&15, row = (lane>>4)*4 + reg
    // store bf16 H and accumulate column sum/sumsq partials (OOB rows masked)
    float* st = (float*)smem;   // [2][4 wv][128 col] : sum then sq (4KB)
#pragma unroll
    for (int nf = 0; nf < 8; ++nf) {
        int c = nf * 16 + li;
        float bb = bl[c];
        float ls = 0.f, lq = 0.f;
#pragma unroll
        for (int m = 0; m < 2; ++m) {
            int row0 = bm + wv * 32 + m * 16 + hi * 4;
#pragma unroll
            for (int j = 0; j < 4; ++j) {
                int row = row0 + j;
                if (row < N_NODES) {
                    float v = acc[m][nf][j] + bb;
                    Hb[(size_t)row * HDIM + c] = f2b(v);
                    ls += v; lq += v * v;
                }
            }
        }
        ls += __shfl_xor(ls, 16); ls += __shfl_xor(ls, 32);
        lq += __shfl_xor(lq, 16); lq += __shfl_xor(lq, 32);
        if (hi == 0) {
            st[wv * 128 + c] = ls;
            st[512 + wv * 128 + c] = lq;
        }
    }
    __syncthreads();
    if (tid < 128) {
        float s = st[tid] + st[128 + tid] + st[256 + tid] + st[384 + tid];
        pstat[blockIdx.x * 256 + tid] = s;
    } else {
        int c = tid - 128;
        float q = st[512 + c] + st[640 + c] + st[768 + c] + st[896 + c];
        pstat[blockIdx.x * 256 + tid] = q;
    }
}

__global__ void __launch_bounds__(256) k_red1(const float* __restrict__ pstat,
                                              float* __restrict__ red32) {
    int c = threadIdx.x, b = blockIdx.x;
    float s = 0.f;
    for (int r = b; r < NBLK_G; r += 32) s += pstat[r * 256 + c];
    red32[b * 256 + c] = s;
}

__global__ void __launch_bounds__(128) k_stats_final(const float* __restrict__ red32,
                                                     const float* __restrict__ gamma,
                                                     const float* __restrict__ beta,
                                                     float* __restrict__ scsh) {
    int c = threadIdx.x;
    float s = 0.f, q = 0.f;
    for (int r = 0; r < 32; ++r) { s += red32[r * 256 + c]; q += red32[r * 256 + 128 + c]; }
    float mu = s / (float)N_NODES;
    float var = q / (float)N_NODES - mu * mu;
    float rs = rsqrtf(var + BN_EPS);
    float sc = gamma[c] * rs;
    scsh[c] = sc;
    scsh[HDIM + c] = beta[c] - mu * sc;
}

// read Hb (bf16), write next activation Xb (bf16)
__global__ void __launch_bounds__(256) k_bn_relu(const unsigned short* __restrict__ Hb,
                                                 const float* __restrict__ scsh,
                                                 unsigned short* __restrict__ Xb) {
    int idx = blockIdx.x * 256 + threadIdx.x;          // ushort8 index, < N*H/8
    int c8 = (idx & 15) * 8;
    short8v v = ((const short8v*)Hb)[idx];
    short8v o;
#pragma unroll
    for (int j = 0; j < 8; ++j) {
        float f = b2f((unsigned short)v[j]) * scsh[c8 + j] + scsh[HDIM + c8 + j];
        o[j] = (short)f2b(fmaxf(0.f, f));
    }
    ((short8v*)Xb)[idx] = o;
}

// ---------------- pooling + classifier ----------------

__global__ void k_gbound(const int* __restrict__ batch, int* __restrict__ gb) {
    int t = blockIdx.x * 64 + threadIdx.x;
    if (t > NGRAPH) return;
    int lo = 0, hi = N_NODES;
    while (lo < hi) { int mid = (lo + hi) >> 1; if (batch[mid] < t) lo = mid + 1; else hi = mid; }
    gb[t] = lo;
}

__global__ void __launch_bounds__(128) k_pool_part(const unsigned short* __restrict__ Xb,
                                                   const int* __restrict__ gb,
                                                   float* __restrict__ ppart) {
    int g = blockIdx.x, sp = blockIdx.y;
    int c = threadIdx.x;
    int s = gb[g], e = gb[g + 1];
    float acc = 0.f;
    for (int i = s + sp; i < e; i += POOL_SPLIT)
        acc += b2f(Xb[(size_t)i * HDIM + c]);
    ppart[(g * POOL_SPLIT + sp) * HDIM + c] = acc;
}

__global__ void __launch_bounds__(128) k_pool_final(const int* __restrict__ gb,
                                                    const float* __restrict__ ppart,
                                                    float* __restrict__ pooled) {
    int g = blockIdx.x, c = threadIdx.x;
    float s = 0.f;
    for (int sp = 0; sp < POOL_SPLIT; ++sp) s += ppart[(g * POOL_SPLIT + sp) * HDIM + c];
    int cnt = gb[g + 1] - gb[g]; if (cnt < 1) cnt = 1;
    pooled[g * HDIM + c] = s / (float)cnt;
}

__global__ void __launch_bounds__(128) k_lin(const float* __restrict__ pooled,
                                             const float* __restrict__ W,
                                             const float* __restrict__ bvec,
                                             float* __restrict__ out) {
    __shared__ float p[HDIM];
    int g = blockIdx.x, t = threadIdx.x;
    p[t] = pooled[g * HDIM + t];
    __syncthreads();
    if (t < NCLASS) {
        float acc = bvec[t];
        for (int k = 0; k < HDIM; ++k) acc += p[k] * W[k * NCLASS + t];
        out[g * NCLASS + t] = acc;
    }
}

// ---------------- launch ----------------

extern "C" void kernel_launch(void* const* d_in, const int* in_sizes, int n_in,
                              void* d_out, int out_size, void* d_ws, size_t ws_size,
                              hipStream_t stream) {
    const float* x     = (const float*)d_in[0];
    const int*   eidx  = (const int*)d_in[1];
    const int*   batch = (const int*)d_in[2];
    const float* Wl    = (const float*)d_in[3];
    const float* bl    = (const float*)d_in[4];
    const float* Wr    = (const float*)d_in[5];
    const float* gamma = (const float*)d_in[6];
    const float* beta  = (const float*)d_in[7];
    const float* linW  = (const float*)d_in[8];
    const float* linb  = (const float*)d_in[9];
    float* out = (float*)d_out;

    const int* src = eidx;
    const int* dst = eidx + N_EDGES;

    // workspace layout (256B-aligned chunks)
    char* p = (char*)d_ws;
    auto alloc = [&](size_t bytes) { char* r = p; p += (bytes + 255) & ~(size_t)255; return r; };
    unsigned short* Xb   = (unsigned short*)alloc((size_t)N_NODES * HDIM * 2);
    unsigned short* AGGb = (unsigned short*)alloc((size_t)N_NODES * HDIM * 2);
    unsigned short* Hb   = (unsigned short*)alloc((size_t)N_NODES * HDIM * 2);
    unsigned short* Wtb  = (unsigned short*)alloc((size_t)NLAYER * 2 * HDIM * HDIM * 2);
    int* row_off = (int*)alloc((N_NODES + 2) * 4);
    int* deg     = (int*)alloc(N_NODES * 4);
    int* cursor  = (int*)alloc(N_NODES * 4);
    int* col     = (int*)alloc((size_t)N_EDGES * 4);
    int* part    = (int*)alloc(SCAN_NB * 4);
    int* gb      = (int*)alloc((NGRAPH + 2) * 4);
    float* pstat = (float*)alloc((size_t)NBLK_G * 256 * 4);
    float* red32 = (float*)alloc(32 * 256 * 4);
    float* scsh  = (float*)alloc(2 * HDIM * 4);
    float* ppart = (float*)alloc((size_t)NGRAPH * POOL_SPLIT * HDIM * 4);
    float* pooled= (float*)alloc(NGRAPH * HDIM * 4);

    // ---- CSR build ----
    hipMemsetAsync(deg, 0, N_NODES * sizeof(int), stream);
    hipMemsetAsync(cursor, 0, N_NODES * sizeof(int), stream);
    k_deg<<<(N_EDGES + 255) / 256, 256, 0, stream>>>(dst, deg);
    k_blocksum<<<SCAN_NB, 256, 0, stream>>>(deg, part);
    k_scanpart<<<1, 64, 0, stream>>>(part);
    k_scan2<<<SCAN_NB, 256, 0, stream>>>(deg, part, row_off);
    k_fill<<<(N_EDGES + 255) / 256, 256, 0, stream>>>(src, dst, row_off, cursor, col);

    // ---- one-time converts ----
    k_cvt_x<<<N_NODES * HDIM / 4 / 256, 256, 0, stream>>>(x, Xb);
    k_cvt_w<<<NLAYER * 2 * HDIM * HDIM / 256, 256, 0, stream>>>(Wl, Wr, Wtb);
    k_gbound<<<3, 64, 0, stream>>>(batch, gb);

    // ---- layers ----
    for (int l = 0; l < NLAYER; ++l) {
        k_agg<<<N_NODES / 16, 256, 0, stream>>>(Xb, row_off, col, AGGb);
        k_gemm_f<<<NBLK_G, 256, 0, stream>>>(
            AGGb, Xb, Wtb + (size_t)l * 2 * HDIM * HDIM, bl + (size_t)l * HDIM, Hb, pstat);
        k_red1<<<32, 256, 0, stream>>>(pstat, red32);
        k_stats_final<<<1, 128, 0, stream>>>(red32, gamma + (size_t)l * HDIM,
                                             beta + (size_t)l * HDIM, scsh);
        k_bn_relu<<<N_NODES * HDIM / 8 / 256, 256, 0, stream>>>(Hb, scsh, Xb);
    }

    // ---- pool + classifier ----
    k_pool_part<<<dim3(NGRAPH, POOL_SPLIT), 128, 0, stream>>>(Xb, gb, ppart);
    k_pool_final<<<NGRAPH, 128, 0, stream>>>(gb, ppart, pooled);
    k_lin<<<NGRAPH, 128, 0, stream>>>(pooled, linW, linb, out);
}

// Round 4
// 834.112 us; speedup vs baseline: 2.8735x; 1.0678x over previous
//
#include <hip/hip_runtime.h>
#include <hip/hip_bf16.h>

#define N_NODES 100000
#define N_EDGES 1600000
#define HDIM    128
#define NLAYER  6
#define NGRAPH  128
#define NCLASS  10
#define BN_EPS  1e-5f

#define SCAN_CHUNK 1024
#define SCAN_NB    ((N_NODES + SCAN_CHUNK - 1) / SCAN_CHUNK)   // 98
#define POOL_SPLIT 16
#define BUCKET_W 12500                                          // nodes per XCD bucket

#define GBM 128
#define NBLK_G ((N_NODES + GBM - 1) / GBM)                     // 782

typedef __attribute__((ext_vector_type(8))) short short8v;
typedef __attribute__((ext_vector_type(4))) float f32x4;

__device__ __forceinline__ float b2f(unsigned short h) {
    return __uint_as_float(((unsigned int)h) << 16);
}
__device__ __forceinline__ unsigned short f2b(float f) {
    unsigned int u = __float_as_uint(f);
    u += 0x7FFF + ((u >> 16) & 1);          // RNE
    return (unsigned short)(u >> 16);
}
__device__ __forceinline__ void gl_lds16(const void* g, void* l) {
    __builtin_amdgcn_global_load_lds((const __attribute__((address_space(1))) unsigned int*)g,
                                     (__attribute__((address_space(3))) unsigned int*)l,
                                     16, 0, 0);
}
__device__ __forceinline__ short8v bn_pack(short8v v, float4 scA, float4 scB,
                                           float4 shA, float4 shB) {
    short8v o;
    o[0] = (short)f2b(fmaxf(0.f, b2f((unsigned short)v[0]) * scA.x + shA.x));
    o[1] = (short)f2b(fmaxf(0.f, b2f((unsigned short)v[1]) * scA.y + shA.y));
    o[2] = (short)f2b(fmaxf(0.f, b2f((unsigned short)v[2]) * scA.z + shA.z));
    o[3] = (short)f2b(fmaxf(0.f, b2f((unsigned short)v[3]) * scA.w + shA.w));
    o[4] = (short)f2b(fmaxf(0.f, b2f((unsigned short)v[4]) * scB.x + shB.x));
    o[5] = (short)f2b(fmaxf(0.f, b2f((unsigned short)v[5]) * scB.y + shB.y));
    o[6] = (short)f2b(fmaxf(0.f, b2f((unsigned short)v[6]) * scB.z + shB.z));
    o[7] = (short)f2b(fmaxf(0.f, b2f((unsigned short)v[7]) * scB.w + shB.w));
    return o;
}

// ---------------- CSR build (XCD-bucketed writes) ----------------

__global__ void __launch_bounds__(256) k_deg_b(const int* __restrict__ dst,
                                               int* __restrict__ deg) {
    int res = blockIdx.x & 7;
    int bi  = blockIdx.x >> 3;
    const int stride = (gridDim.x >> 3) * 256;
    for (int e = bi * 256 + threadIdx.x; e < N_EDGES; e += stride) {
        int d = dst[e];
        if (d / BUCKET_W == res) atomicAdd(&deg[d], 1);
    }
}

__global__ void __launch_bounds__(256) k_fill_b(const int* __restrict__ src,
                                                const int* __restrict__ dst,
                                                const int* __restrict__ row_off,
                                                int* __restrict__ cursor,
                                                int* __restrict__ col) {
    int res = blockIdx.x & 7;
    int bi  = blockIdx.x >> 3;
    const int stride = (gridDim.x >> 3) * 256;
    for (int e = bi * 256 + threadIdx.x; e < N_EDGES; e += stride) {
        int d = dst[e];
        if (d / BUCKET_W == res) {
            int pos = row_off[d] + atomicAdd(&cursor[d], 1);
            col[pos] = src[e];
        }
    }
}

__global__ void k_blocksum(const int* __restrict__ deg, int* __restrict__ partial) {
    int b = blockIdx.x, t = threadIdx.x;
    int s = 0;
    for (int i = 0; i < 4; ++i) {
        int g = b * SCAN_CHUNK + t * 4 + i;
        if (g < N_NODES) s += deg[g];
    }
    __shared__ int red[256];
    red[t] = s; __syncthreads();
    for (int off = 128; off > 0; off >>= 1) {
        if (t < off) red[t] += red[t + off];
        __syncthreads();
    }
    if (t == 0) partial[b] = red[0];
}

__global__ void k_scanpart(int* __restrict__ partial) {
    if (threadIdx.x == 0 && blockIdx.x == 0) {
        int acc = 0;
        for (int i = 0; i < SCAN_NB; ++i) { int v = partial[i]; partial[i] = acc; acc += v; }
    }
}

__global__ void k_scan2(const int* __restrict__ deg, const int* __restrict__ partial,
                        int* __restrict__ row_off) {
    int b = blockIdx.x, t = threadIdx.x;
    int base = b * SCAN_CHUNK;
    int v[4]; int s = 0;
    for (int i = 0; i < 4; ++i) {
        int g = base + t * 4 + i;
        v[i] = (g < N_NODES) ? deg[g] : 0;
        s += v[i];
    }
    __shared__ int ts[256];
    ts[t] = s; __syncthreads();
    for (int off = 1; off < 256; off <<= 1) {
        int x = (t >= off) ? ts[t - off] : 0;
        __syncthreads();
        ts[t] += x;
        __syncthreads();
    }
    int excl = (t > 0 ? ts[t - 1] : 0) + partial[b];
    for (int i = 0; i < 4; ++i) {
        int g = base + t * 4 + i;
        if (g < N_NODES) row_off[g] = excl;
        excl += v[i];
    }
    if (b == 0 && t == 0) row_off[N_NODES] = N_EDGES;
}

// ---------------- one-time converts ----------------

__global__ void __launch_bounds__(256) k_cvt_x(const float* __restrict__ x,
                                               unsigned short* __restrict__ Xb) {
    int idx = blockIdx.x * 256 + threadIdx.x;          // < N*H/4
    float4 v = ((const float4*)x)[idx];
    ushort4 o = { f2b(v.x), f2b(v.y), f2b(v.z), f2b(v.w) };
    ((ushort4*)Xb)[idx] = o;
}

// Wtb[l][n][kk] (kk<128 -> Wl[l][kk][n], else Wr[l][kk-128][n]), bf16
__global__ void __launch_bounds__(256) k_cvt_w(const float* __restrict__ Wl,
                                               const float* __restrict__ Wr,
                                               unsigned short* __restrict__ Wtb) {
    int idx = blockIdx.x * 256 + threadIdx.x;          // < 6*128*256
    int kk = idx & 255;
    int n  = (idx >> 8) & 127;
    int l  = idx >> 15;
    float v = (kk < HDIM) ? Wl[l * HDIM * HDIM + kk * HDIM + n]
                          : Wr[l * HDIM * HDIM + (kk - HDIM) * HDIM + n];
    Wtb[idx] = f2b(v);
}

// ---------------- aggregation ----------------

// 16 nodes per block, 16 threads per node, ushort8 (8 channels, 16B) per thread
__global__ void __launch_bounds__(256) k_agg(const unsigned short* __restrict__ Xb,
                                             const int* __restrict__ row_off,
                                             const int* __restrict__ col,
                                             unsigned short* __restrict__ AGGb) {
    int node = blockIdx.x * 16 + (threadIdx.x >> 4);
    int t = threadIdx.x & 15;
    int s = row_off[node], e = row_off[node + 1];
    float a[8] = {};
    int p = s;
    for (; p + 4 <= e; p += 4) {
        int n0 = col[p], n1 = col[p + 1], n2 = col[p + 2], n3 = col[p + 3];
        short8v v0 = *(const short8v*)(Xb + (size_t)n0 * HDIM + t * 8);
        short8v v1 = *(const short8v*)(Xb + (size_t)n1 * HDIM + t * 8);
        short8v v2 = *(const short8v*)(Xb + (size_t)n2 * HDIM + t * 8);
        short8v v3 = *(const short8v*)(Xb + (size_t)n3 * HDIM + t * 8);
#pragma unroll
        for (int j = 0; j < 8; ++j)
            a[j] += (b2f((unsigned short)v0[j]) + b2f((unsigned short)v1[j]))
                  + (b2f((unsigned short)v2[j]) + b2f((unsigned short)v3[j]));
    }
    for (; p < e; ++p) {
        int n0 = col[p];
        short8v v0 = *(const short8v*)(Xb + (size_t)n0 * HDIM + t * 8);
#pragma unroll
        for (int j = 0; j < 8; ++j) a[j] += b2f((unsigned short)v0[j]);
    }
    float w = (e > s) ? 1.0f / (float)(e - s) : 0.f;
    short8v o;
#pragma unroll
    for (int j = 0; j < 8; ++j) o[j] = (short)f2b(a[j] * w);
    *(short8v*)(AGGb + (size_t)node * HDIM + t * 8) = o;
}

// gather raw H, apply BN(scsh)+ReLU on the fly
__global__ void __launch_bounds__(256) k_agg_bn(const unsigned short* __restrict__ Hb,
                                                const float* __restrict__ scsh,
                                                const int* __restrict__ row_off,
                                                const int* __restrict__ col,
                                                unsigned short* __restrict__ AGGb) {
    int node = blockIdx.x * 16 + (threadIdx.x >> 4);
    int t = threadIdx.x & 15;
    int c8 = t * 8;
    float4 scA = *(const float4*)&scsh[c8];
    float4 scB = *(const float4*)&scsh[c8 + 4];
    float4 shA = *(const float4*)&scsh[HDIM + c8];
    float4 shB = *(const float4*)&scsh[HDIM + c8 + 4];
    float sc[8] = { scA.x, scA.y, scA.z, scA.w, scB.x, scB.y, scB.z, scB.w };
    float sh[8] = { shA.x, shA.y, shA.z, shA.w, shB.x, shB.y, shB.z, shB.w };
    int s = row_off[node], e = row_off[node + 1];
    float a[8] = {};
    int p = s;
    for (; p + 4 <= e; p += 4) {
        int n0 = col[p], n1 = col[p + 1], n2 = col[p + 2], n3 = col[p + 3];
        short8v v0 = *(const short8v*)(Hb + (size_t)n0 * HDIM + c8);
        short8v v1 = *(const short8v*)(Hb + (size_t)n1 * HDIM + c8);
        short8v v2 = *(const short8v*)(Hb + (size_t)n2 * HDIM + c8);
        short8v v3 = *(const short8v*)(Hb + (size_t)n3 * HDIM + c8);
#pragma unroll
        for (int j = 0; j < 8; ++j) {
            a[j] += fmaxf(0.f, b2f((unsigned short)v0[j]) * sc[j] + sh[j]);
            a[j] += fmaxf(0.f, b2f((unsigned short)v1[j]) * sc[j] + sh[j]);
            a[j] += fmaxf(0.f, b2f((unsigned short)v2[j]) * sc[j] + sh[j]);
            a[j] += fmaxf(0.f, b2f((unsigned short)v3[j]) * sc[j] + sh[j]);
        }
    }
    for (; p < e; ++p) {
        int n0 = col[p];
        short8v v0 = *(const short8v*)(Hb + (size_t)n0 * HDIM + c8);
#pragma unroll
        for (int j = 0; j < 8; ++j)
            a[j] += fmaxf(0.f, b2f((unsigned short)v0[j]) * sc[j] + sh[j]);
    }
    float w = (e > s) ? 1.0f / (float)(e - s) : 0.f;
    short8v o;
#pragma unroll
    for (int j = 0; j < 8; ++j) o[j] = (short)f2b(a[j] * w);
    *(short8v*)(AGGb + (size_t)node * HDIM + c8) = o;
}

// ---------------- GEMMs (128 rows/block, K=256, dbuf, fused BN stats) ----------------

// layer 0: A = [AGGb | Xb], both gl_lds
__global__ void __launch_bounds__(256) k_gemm_l0(const unsigned short* __restrict__ AGGb,
                                                 const unsigned short* __restrict__ Xb,
                                                 const unsigned short* __restrict__ Wtb,
                                                 const float* __restrict__ bl,
                                                 unsigned short* __restrict__ Hb,
                                                 float* __restrict__ pstat) {
    __shared__ __align__(16) char smem[32768];
    const int tid  = threadIdx.x;
    const int bm   = blockIdx.x * GBM;
    const int wv   = tid >> 6;
    const int lane = tid & 63;
    const int li   = lane & 15, hi = lane >> 4;

    f32x4 acc[2][8] = {};

    auto stage = [&](int b, int step) {
        const unsigned short* Asrc = (step < 4) ? AGGb : Xb;
        const int kk0 = (step & 3) * 32;
        char* base = smem + b * 16384;
#pragma unroll
        for (int q = 0; q < 2; ++q) {
            int s = q * 256 + tid;
            int r = s >> 2, sk = s & 3;
            int row = bm + r; if (row >= N_NODES) row = N_NODES - 1;
            gl_lds16((const char*)(Asrc + (size_t)row * HDIM + kk0) + (((sk ^ (r & 3)) & 3) << 4),
                     base + (q * 4 + wv) * 1024);
        }
        const int k0 = step * 32;
#pragma unroll
        for (int q = 0; q < 2; ++q) {
            int s = q * 256 + tid;
            int n = s >> 2, sk = s & 3;
            gl_lds16((const char*)(Wtb + (size_t)n * 256 + k0) + (((sk ^ (n & 3)) & 3) << 4),
                     base + 8192 + (q * 4 + wv) * 1024);
        }
    };

    stage(0, 0);
    __syncthreads();

    int buf = 0;
    for (int step = 0; step < 8; ++step) {
        if (step < 7) stage(buf ^ 1, step + 1);
        char* bA = smem + buf * 16384;
        char* bW = bA + 8192;
        short8v afr[2], bfr[8];
#pragma unroll
        for (int m = 0; m < 2; ++m) {
            int r = wv * 32 + m * 16 + li;
            afr[m] = *(const short8v*)(bA + r * 64 + ((hi ^ (r & 3)) << 4));
        }
#pragma unroll
        for (int nf = 0; nf < 8; ++nf) {
            int n = nf * 16 + li;
            bfr[nf] = *(const short8v*)(bW + n * 64 + ((hi ^ (n & 3)) << 4));
        }
#pragma unroll
        for (int m = 0; m < 2; ++m)
#pragma unroll
            for (int nf = 0; nf < 8; ++nf)
                acc[m][nf] = __builtin_amdgcn_mfma_f32_16x16x32_bf16(afr[m], bfr[nf],
                                                                     acc[m][nf], 0, 0, 0);
        __syncthreads();
        buf ^= 1;
    }

    float* st = (float*)smem;
#pragma unroll
    for (int nf = 0; nf < 8; ++nf) {
        int c = nf * 16 + li;
        float bb = bl[c];
        float ls = 0.f, lq = 0.f;
#pragma unroll
        for (int m = 0; m < 2; ++m) {
            int row0 = bm + wv * 32 + m * 16 + hi * 4;
#pragma unroll
            for (int j = 0; j < 4; ++j) {
                int row = row0 + j;
                if (row < N_NODES) {
                    float v = acc[m][nf][j] + bb;
                    Hb[(size_t)row * HDIM + c] = f2b(v);
                    ls += v; lq += v * v;
                }
            }
        }
        ls += __shfl_xor(ls, 16); ls += __shfl_xor(ls, 32);
        lq += __shfl_xor(lq, 16); lq += __shfl_xor(lq, 32);
        if (hi == 0) {
            st[wv * 128 + c] = ls;
            st[512 + wv * 128 + c] = lq;
        }
    }
    __syncthreads();
    if (tid < 128) {
        float s = st[tid] + st[128 + tid] + st[256 + tid] + st[384 + tid];
        pstat[blockIdx.x * 256 + tid] = s;
    } else {
        int c = tid - 128;
        float q = st[512 + c] + st[640 + c] + st[768 + c] + st[896 + c];
        pstat[blockIdx.x * 256 + tid] = q;
    }
}

// layers 1..5: A = [AGGb | bn_relu(Hprev)] — second half reg-staged with transform
__global__ void __launch_bounds__(256) k_gemm_fuse(const unsigned short* __restrict__ AGGb,
                                                   const unsigned short* __restrict__ Hprev,
                                                   const float* __restrict__ scsh,
                                                   const unsigned short* __restrict__ Wtb,
                                                   const float* __restrict__ bl,
                                                   unsigned short* __restrict__ Hb,
                                                   float* __restrict__ pstat) {
    __shared__ __align__(16) char smem[32768];
    const int tid  = threadIdx.x;
    const int bm   = blockIdx.x * GBM;
    const int wv   = tid >> 6;
    const int lane = tid & 63;
    const int li   = lane & 15, hi = lane >> 4;
    const int rr   = tid >> 2;            // 0..63
    const int sk   = tid & 3;
    const int swz  = ((sk ^ (rr & 3)) << 4);   // r&3 identical for r=rr and r=rr+64

    f32x4 acc[2][8] = {};

    auto stageW = [&](char* base, int step) {
        const int k0 = step * 32;
#pragma unroll
        for (int q = 0; q < 2; ++q) {
            int n = q * 64 + rr;
            gl_lds16((const char*)(Wtb + (size_t)n * 256 + k0) + swz,
                     base + 8192 + (q * 4 + wv) * 1024);
        }
    };
    auto stageA = [&](char* base, int step) {     // AGGb, steps 0..3
        const int kk0 = step * 32;
#pragma unroll
        for (int q = 0; q < 2; ++q) {
            int r = q * 64 + rr;
            int row = bm + r; if (row >= N_NODES) row = N_NODES - 1;
            gl_lds16((const char*)(AGGb + (size_t)row * HDIM + kk0) + swz,
                     base + (q * 4 + wv) * 1024);
        }
    };

    stageA(smem, 0); stageW(smem, 0);
    __syncthreads();

    int buf = 0;
    for (int step = 0; step < 8; ++step) {
        char* cur = smem + buf * 16384;
        char* nxt = smem + (buf ^ 1) * 16384;
        const int ns = step + 1;
        short8v rv0, rv1;
        int c0 = 0;
        bool regstage = false;
        if (step < 7) {
            stageW(nxt, ns);
            if (ns < 4) {
                stageA(nxt, ns);
            } else {
                regstage = true;
                c0 = ns * 32 - 128 + sk * 8;
                int row0 = bm + rr;      if (row0 >= N_NODES) row0 = N_NODES - 1;
                int row1 = bm + 64 + rr; if (row1 >= N_NODES) row1 = N_NODES - 1;
                rv0 = *(const short8v*)(Hprev + (size_t)row0 * HDIM + c0);
                rv1 = *(const short8v*)(Hprev + (size_t)row1 * HDIM + c0);
            }
        }

        short8v afr[2], bfr[8];
#pragma unroll
        for (int m = 0; m < 2; ++m) {
            int r = wv * 32 + m * 16 + li;
            afr[m] = *(const short8v*)(cur + r * 64 + ((hi ^ (r & 3)) << 4));
        }
#pragma unroll
        for (int nf = 0; nf < 8; ++nf) {
            int n = nf * 16 + li;
            bfr[nf] = *(const short8v*)(cur + 8192 + n * 64 + ((hi ^ (n & 3)) << 4));
        }
#pragma unroll
        for (int m = 0; m < 2; ++m)
#pragma unroll
            for (int nf = 0; nf < 8; ++nf)
                acc[m][nf] = __builtin_amdgcn_mfma_f32_16x16x32_bf16(afr[m], bfr[nf],
                                                                     acc[m][nf], 0, 0, 0);

        if (regstage) {
            float4 scA = *(const float4*)&scsh[c0];
            float4 scB = *(const float4*)&scsh[c0 + 4];
            float4 shA = *(const float4*)&scsh[HDIM + c0];
            float4 shB = *(const float4*)&scsh[HDIM + c0 + 4];
            *(short8v*)(nxt + rr * 64 + swz)        = bn_pack(rv0, scA, scB, shA, shB);
            *(short8v*)(nxt + (64 + rr) * 64 + swz) = bn_pack(rv1, scA, scB, shA, shB);
        }
        __syncthreads();
        buf ^= 1;
    }

    float* st = (float*)smem;
#pragma unroll
    for (int nf = 0; nf < 8; ++nf) {
        int c = nf * 16 + li;
        float bb = bl[c];
        float ls = 0.f, lq = 0.f;
#pragma unroll
        for (int m = 0; m < 2; ++m) {
            int row0 = bm + wv * 32 + m * 16 + hi * 4;
#pragma unroll
            for (int j = 0; j < 4; ++j) {
                int row = row0 + j;
                if (row < N_NODES) {
                    float v = acc[m][nf][j] + bb;
                    Hb[(size_t)row * HDIM + c] = f2b(v);
                    ls += v; lq += v * v;
                }
            }
        }
        ls += __shfl_xor(ls, 16); ls += __shfl_xor(ls, 32);
        lq += __shfl_xor(lq, 16); lq += __shfl_xor(lq, 32);
        if (hi == 0) {
            st[wv * 128 + c] = ls;
            st[512 + wv * 128 + c] = lq;
        }
    }
    __syncthreads();
    if (tid < 128) {
        float s = st[tid] + st[128 + tid] + st[256 + tid] + st[384 + tid];
        pstat[blockIdx.x * 256 + tid] = s;
    } else {
        int c = tid - 128;
        float q = st[512 + c] + st[640 + c] + st[768 + c] + st[896 + c];
        pstat[blockIdx.x * 256 + tid] = q;
    }
}

__global__ void __launch_bounds__(256) k_red1(const float* __restrict__ pstat,
                                              float* __restrict__ red32) {
    int c = threadIdx.x, b = blockIdx.x;
    float s = 0.f;
    for (int r = b; r < NBLK_G; r += 32) s += pstat[r * 256 + c];
    red32[b * 256 + c] = s;
}

__global__ void __launch_bounds__(128) k_stats_final(const float* __restrict__ red32,
                                                     const float* __restrict__ gamma,
                                                     const float* __restrict__ beta,
                                                     float* __restrict__ scsh) {
    int c = threadIdx.x;
    float s = 0.f, q = 0.f;
    for (int r = 0; r < 32; ++r) { s += red32[r * 256 + c]; q += red32[r * 256 + 128 + c]; }
    float mu = s / (float)N_NODES;
    float var = q / (float)N_NODES - mu * mu;
    float rs = rsqrtf(var + BN_EPS);
    float sc = gamma[c] * rs;
    scsh[c] = sc;
    scsh[HDIM + c] = beta[c] - mu * sc;
}

// ---------------- pooling + classifier ----------------

__global__ void k_gbound(const int* __restrict__ batch, int* __restrict__ gb) {
    int t = blockIdx.x * 64 + threadIdx.x;
    if (t > NGRAPH) return;
    int lo = 0, hi = N_NODES;
    while (lo < hi) { int mid = (lo + hi) >> 1; if (batch[mid] < t) lo = mid + 1; else hi = mid; }
    gb[t] = lo;
}

// pool over bn_relu(H_final) applied on the fly
__global__ void __launch_bounds__(128) k_pool_part(const unsigned short* __restrict__ Hb,
                                                   const float* __restrict__ scsh,
                                                   const int* __restrict__ gb,
                                                   float* __restrict__ ppart) {
    int g = blockIdx.x, sp = blockIdx.y;
    int c = threadIdx.x;
    float sc = scsh[c], sh = scsh[HDIM + c];
    int s = gb[g], e = gb[g + 1];
    float acc = 0.f;
    for (int i = s + sp; i < e; i += POOL_SPLIT)
        acc += fmaxf(0.f, b2f(Hb[(size_t)i * HDIM + c]) * sc + sh);
    ppart[(g * POOL_SPLIT + sp) * HDIM + c] = acc;
}

__global__ void __launch_bounds__(128) k_pool_final(const int* __restrict__ gb,
                                                    const float* __restrict__ ppart,
                                                    float* __restrict__ pooled) {
    int g = blockIdx.x, c = threadIdx.x;
    float s = 0.f;
    for (int sp = 0; sp < POOL_SPLIT; ++sp) s += ppart[(g * POOL_SPLIT + sp) * HDIM + c];
    int cnt = gb[g + 1] - gb[g]; if (cnt < 1) cnt = 1;
    pooled[g * HDIM + c] = s / (float)cnt;
}

__global__ void __launch_bounds__(128) k_lin(const float* __restrict__ pooled,
                                             const float* __restrict__ W,
                                             const float* __restrict__ bvec,
                                             float* __restrict__ out) {
    __shared__ float p[HDIM];
    int g = blockIdx.x, t = threadIdx.x;
    p[t] = pooled[g * HDIM + t];
    __syncthreads();
    if (t < NCLASS) {
        float acc = bvec[t];
        for (int k = 0; k < HDIM; ++k) acc += p[k] * W[k * NCLASS + t];
        out[g * NCLASS + t] = acc;
    }
}

// ---------------- launch ----------------

extern "C" void kernel_launch(void* const* d_in, const int* in_sizes, int n_in,
                              void* d_out, int out_size, void* d_ws, size_t ws_size,
                              hipStream_t stream) {
    const float* x     = (const float*)d_in[0];
    const int*   eidx  = (const int*)d_in[1];
    const int*   batch = (const int*)d_in[2];
    const float* Wl    = (const float*)d_in[3];
    const float* bl    = (const float*)d_in[4];
    const float* Wr    = (const float*)d_in[5];
    const float* gamma = (const float*)d_in[6];
    const float* beta  = (const float*)d_in[7];
    const float* linW  = (const float*)d_in[8];
    const float* linb  = (const float*)d_in[9];
    float* out = (float*)d_out;

    const int* src = eidx;
    const int* dst = eidx + N_EDGES;

    char* p = (char*)d_ws;
    auto alloc = [&](size_t bytes) { char* r = p; p += (bytes + 255) & ~(size_t)255; return r; };
    unsigned short* Xb   = (unsigned short*)alloc((size_t)N_NODES * HDIM * 2);
    unsigned short* AGGb = (unsigned short*)alloc((size_t)N_NODES * HDIM * 2);
    unsigned short* HbA  = (unsigned short*)alloc((size_t)N_NODES * HDIM * 2);
    unsigned short* HbB  = (unsigned short*)alloc((size_t)N_NODES * HDIM * 2);
    unsigned short* Wtb  = (unsigned short*)alloc((size_t)NLAYER * 2 * HDIM * HDIM * 2);
    int* row_off = (int*)alloc((N_NODES + 2) * 4);
    int* deg     = (int*)alloc(N_NODES * 4);
    int* cursor  = (int*)alloc(N_NODES * 4);
    int* col     = (int*)alloc((size_t)N_EDGES * 4);
    int* part    = (int*)alloc(SCAN_NB * 4);
    int* gb      = (int*)alloc((NGRAPH + 2) * 4);
    float* pstat = (float*)alloc((size_t)NBLK_G * 256 * 4);
    float* red32 = (float*)alloc(32 * 256 * 4);
    float* scsh  = (float*)alloc(2 * HDIM * 4);
    float* ppart = (float*)alloc((size_t)NGRAPH * POOL_SPLIT * HDIM * 4);
    float* pooled= (float*)alloc(NGRAPH * HDIM * 4);

    // ---- CSR build (XCD-bucketed) ----
    hipMemsetAsync(deg, 0, N_NODES * sizeof(int), stream);
    hipMemsetAsync(cursor, 0, N_NODES * sizeof(int), stream);
    k_deg_b<<<1024, 256, 0, stream>>>(dst, deg);
    k_blocksum<<<SCAN_NB, 256, 0, stream>>>(deg, part);
    k_scanpart<<<1, 64, 0, stream>>>(part);
    k_scan2<<<SCAN_NB, 256, 0, stream>>>(deg, part, row_off);
    k_fill_b<<<1024, 256, 0, stream>>>(src, dst, row_off, cursor, col);

    // ---- one-time converts ----
    k_cvt_x<<<N_NODES * HDIM / 4 / 256, 256, 0, stream>>>(x, Xb);
    k_cvt_w<<<NLAYER * 2 * HDIM * HDIM / 256, 256, 0, stream>>>(Wl, Wr, Wtb);
    k_gbound<<<3, 64, 0, stream>>>(batch, gb);

    // ---- layer 0 ----
    k_agg<<<N_NODES / 16, 256, 0, stream>>>(Xb, row_off, col, AGGb);
    k_gemm_l0<<<NBLK_G, 256, 0, stream>>>(AGGb, Xb, Wtb, bl, HbA, pstat);
    k_red1<<<32, 256, 0, stream>>>(pstat, red32);
    k_stats_final<<<1, 128, 0, stream>>>(red32, gamma, beta, scsh);

    // ---- layers 1..5 ----
    unsigned short* Hcur = HbA;
    for (int l = 1; l < NLAYER; ++l) {
        unsigned short* Hout = (l & 1) ? HbB : HbA;
        k_agg_bn<<<N_NODES / 16, 256, 0, stream>>>(Hcur, scsh, row_off, col, AGGb);
        k_gemm_fuse<<<NBLK_G, 256, 0, stream>>>(
            AGGb, Hcur, scsh, Wtb + (size_t)l * 2 * HDIM * HDIM, bl + (size_t)l * HDIM,
            Hout, pstat);
        k_red1<<<32, 256, 0, stream>>>(pstat, red32);
        k_stats_final<<<1, 128, 0, stream>>>(red32, gamma + (size_t)l * HDIM,
                                             beta + (size_t)l * HDIM, scsh);
        Hcur = Hout;
    }

    // ---- pool + classifier ----
    k_pool_part<<<dim3(NGRAPH, POOL_SPLIT), 128, 0, stream>>>(Hcur, scsh, gb, ppart);
    k_pool_final<<<NGRAPH, 128, 0, stream>>>(gb, ppart, pooled);
    k_lin<<<NGRAPH, 128, 0, stream>>>(pooled, linW, linb, out);
}